// Round 1
// baseline (574.155 us; speedup 1.0000x reference)
//
#include <hip/hip_runtime.h>
#include <stdint.h>

typedef unsigned short u16;
typedef __attribute__((ext_vector_type(8))) short bf16x8;      // 8 bf16 = 4 VGPRs
typedef __attribute__((ext_vector_type(8))) unsigned short u16x8;
typedef __attribute__((ext_vector_type(4))) float f32x4;

#define B_  2
#define T_  4096
#define C_  2048
#define NH  16
#define NKV 4
#define HD  128

__device__ __forceinline__ u16 f2bf(float f) {
  union { float f; uint32_t u; } v; v.f = f;
  uint32_t u = v.u;
  u += 0x7fffu + ((u >> 16) & 1u);   // RNE
  return (u16)(u >> 16);
}
__device__ __forceinline__ float bf2f(u16 h) {
  union { uint32_t u; float f; } v; v.u = ((uint32_t)h) << 16;
  return v.f;
}

// ---------------- f32 -> bf16 convert ----------------
__global__ void cvt_f32_bf16(const float* __restrict__ src, u16* __restrict__ dst, int n) {
  int i = (blockIdx.x * blockDim.x + threadIdx.x) * 4;
  if (i >= n) return;
  float4 v = *(const float4*)(src + i);
  ushort4 o;
  o.x = f2bf(v.x); o.y = f2bf(v.y); o.z = f2bf(v.z); o.w = f2bf(v.w);
  *(ushort4*)(dst + i) = o;
}

// ---------------- in-place RoPE on qkv buffer [B*T][3072] ----------------
__global__ void rope_kernel(u16* __restrict__ qkv, const float* __restrict__ cache) {
  const int PH = (NH + NKV) * (HD / 2);   // 1280 pairs per row (q heads then kv heads)
  long idx = (long)blockIdx.x * blockDim.x + threadIdx.x;
  if (idx >= (long)B_ * T_ * PH) return;
  int row = (int)(idx / PH);
  int rem = (int)(idx % PH);
  int hh = rem >> 6;        // 0..19 ; q cols 0..2047, k cols 2048..2559 — contiguous as hh*128
  int i  = rem & 63;
  int t  = row & (T_ - 1);
  float c = cache[t * 128 + 2 * i];
  float s = cache[t * 128 + 2 * i + 1];
  u16* p = qkv + (long)row * 3072 + hh * HD + 2 * i;
  float x0 = bf2f(p[0]), x1 = bf2f(p[1]);
  p[0] = f2bf(x0 * c - x1 * s);
  p[1] = f2bf(x0 * s + x1 * c);
}

// ---------------- bf16 GEMM: C[M][N] = A[M][K] * B[N][K]^T ----------------
// 128x128 tile, BK=32, 4 waves each computing 64x64 via 4x4 mfma_16x16x32 grid.
template <int WRITE_BF16>
__global__ __launch_bounds__(256) void gemm_bt(const u16* __restrict__ A,
                                               const u16* __restrict__ Bw,
                                               void* __restrict__ Cv,
                                               int M, int N, int K) {
  constexpr int BK = 32;
  __shared__ u16 As[128 * BK];
  __shared__ u16 Bs[128 * BK];
  const int tid = threadIdx.x;
  const int wave = tid >> 6, lane = tid & 63;
  const int q4 = lane >> 4, l16 = lane & 15;
  const long m0 = (long)blockIdx.y * 128, n0 = (long)blockIdx.x * 128;
  const int wm = (wave >> 1) * 64, wn = (wave & 1) * 64;
  const int sr = tid >> 1, sc = (tid & 1) * 16;   // each thread stages 16 u16 for A and B
  const u16* Ag = A + (m0 + sr) * K + sc;
  const u16* Bg = Bw + (n0 + sr) * K + sc;
  f32x4 acc[4][4] = {};
  for (int k0 = 0; k0 < K; k0 += BK) {
    u16x8 a0 = *(const u16x8*)(Ag + k0);
    u16x8 a1 = *(const u16x8*)(Ag + k0 + 8);
    u16x8 b0 = *(const u16x8*)(Bg + k0);
    u16x8 b1 = *(const u16x8*)(Bg + k0 + 8);
    *(u16x8*)(As + sr * BK + sc)     = a0;
    *(u16x8*)(As + sr * BK + sc + 8) = a1;
    *(u16x8*)(Bs + sr * BK + sc)     = b0;
    *(u16x8*)(Bs + sr * BK + sc + 8) = b1;
    __syncthreads();
    bf16x8 af[4], bf[4];
#pragma unroll
    for (int i = 0; i < 4; i++)
      af[i] = *(const bf16x8*)(As + (wm + 16 * i + l16) * BK + q4 * 8);
#pragma unroll
    for (int j = 0; j < 4; j++)
      bf[j] = *(const bf16x8*)(Bs + (wn + 16 * j + l16) * BK + q4 * 8);
#pragma unroll
    for (int i = 0; i < 4; i++)
#pragma unroll
      for (int j = 0; j < 4; j++)
        acc[i][j] = __builtin_amdgcn_mfma_f32_16x16x32_bf16(af[i], bf[j], acc[i][j], 0, 0, 0);
    __syncthreads();
  }
  // C/D layout: col = lane&15, row = (lane>>4)*4 + reg   [measured m89]
  if (WRITE_BF16) {
    u16* Cp = (u16*)Cv;
#pragma unroll
    for (int i = 0; i < 4; i++)
#pragma unroll
      for (int j = 0; j < 4; j++)
#pragma unroll
        for (int r = 0; r < 4; r++)
          Cp[(m0 + wm + 16 * i + q4 * 4 + r) * (long)N + n0 + wn + 16 * j + l16] =
              f2bf(acc[i][j][r]);
  } else {
    float* Cp = (float*)Cv;
#pragma unroll
    for (int i = 0; i < 4; i++)
#pragma unroll
      for (int j = 0; j < 4; j++)
#pragma unroll
        for (int r = 0; r < 4; r++)
          Cp[(m0 + wm + 16 * i + q4 * 4 + r) * (long)N + n0 + wn + 16 * j + l16] =
              acc[i][j][r];
  }
}

// ---------------- sliding-window attention ----------------
// grid (NH, T/128, B); block 256 = 4 waves; wave w owns query rows [t0+32w, t0+32w+32)
// K-chunks of 128 keys; online softmax; P round-trips through LDS (aliases K tile).
__global__ __launch_bounds__(256) void attn_kernel(const u16* __restrict__ qkv,
                                                   u16* __restrict__ y) {
  const int h = blockIdx.x, tc = blockIdx.y, b = blockIdx.z;
  const int t0 = tc * 128;
  const int kvh = h >> 2;
  __shared__ u16 KP[128 * 128];   // K chunk [key][d]; later re-used as P [q][key]
  __shared__ u16 Vt[128 * 128];   // V^T chunk [d][key]
  const int tid = threadIdx.x;
  const int wave = tid >> 6, lane = tid & 63;
  const int q4 = lane >> 4, l16 = lane & 15;
  const float scale = 0.08838834764831845f;   // 1/sqrt(128)
  const float LOG2E = 1.4426950408889634f;

  // Q fragments (A-layout: m = lane&15, k = quad*8+j), rows t0+32w+16i+l16
  bf16x8 qf[2][4];
#pragma unroll
  for (int i = 0; i < 2; i++)
#pragma unroll
    for (int ks = 0; ks < 4; ks++) {
      const u16* src = qkv + ((long)(b * T_ + t0 + 32 * wave + 16 * i + l16)) * 3072 +
                       h * HD + ks * 32 + q4 * 8;
      qf[i][ks] = *(const bf16x8*)src;
    }

  f32x4 O[2][8] = {};
  float m_i[2][4], l_i[2][4];
#pragma unroll
  for (int i = 0; i < 2; i++)
#pragma unroll
    for (int r = 0; r < 4; r++) { m_i[i][r] = -1e30f; l_i[i][r] = 0.f; }

  int kstart = t0 - 256; if (kstart < 0) kstart = 0;
  for (int k0 = kstart; k0 <= t0; k0 += 128) {
    __syncthreads();   // prev PV reads of KP/Vt done
    {
      int key = tid & 127, db = (tid >> 7) * 64;
      const u16* kg = qkv + ((long)(b * T_ + k0 + key)) * 3072 + C_ + kvh * HD + db;
      const u16* vg = kg + NKV * HD;   // v is 512 cols after k
#pragma unroll
      for (int j2 = 0; j2 < 8; j2++) {
        u16x8 kk = *(const u16x8*)(kg + 8 * j2);
        *(u16x8*)(&KP[key * 128 + db + 8 * j2]) = kk;
        u16x8 vv = *(const u16x8*)(vg + 8 * j2);
#pragma unroll
        for (int e = 0; e < 8; e++) Vt[(db + 8 * j2 + e) * 128 + key] = vv[e];
      }
    }
    __syncthreads();
    // S = Q K^T : per wave 32 q-rows x 128 keys
    f32x4 S[2][8] = {};
#pragma unroll
    for (int ks = 0; ks < 4; ks++)
#pragma unroll
      for (int j = 0; j < 8; j++) {
        bf16x8 kf = *(const bf16x8*)(&KP[(16 * j + l16) * 128 + ks * 32 + q4 * 8]);
        S[0][j] = __builtin_amdgcn_mfma_f32_16x16x32_bf16(qf[0][ks], kf, S[0][j], 0, 0, 0);
        S[1][j] = __builtin_amdgcn_mfma_f32_16x16x32_bf16(qf[1][ks], kf, S[1][j], 0, 0, 0);
      }
    // scale + band mask + chunk row-max
    float mc[2][4];
#pragma unroll
    for (int i = 0; i < 2; i++)
#pragma unroll
      for (int r = 0; r < 4; r++) mc[i][r] = -1e30f;
#pragma unroll
    for (int i = 0; i < 2; i++)
#pragma unroll
      for (int j = 0; j < 8; j++)
#pragma unroll
        for (int r = 0; r < 4; r++) {
          float s = S[i][j][r] * scale;
          int trow = t0 + 32 * wave + 16 * i + q4 * 4 + r;
          int kcol = k0 + 16 * j + l16;
          bool valid = (kcol <= trow) && (kcol + 255 >= trow);
          s = valid ? s : -1e30f;
          S[i][j][r] = s;
          mc[i][r] = fmaxf(mc[i][r], s);
        }
#pragma unroll
    for (int d = 1; d < 16; d <<= 1)
#pragma unroll
      for (int i = 0; i < 2; i++)
#pragma unroll
        for (int r = 0; r < 4; r++)
          mc[i][r] = fmaxf(mc[i][r], __shfl_xor(mc[i][r], d, 64));
    float alpha[2][4];
#pragma unroll
    for (int i = 0; i < 2; i++)
#pragma unroll
      for (int r = 0; r < 4; r++) {
        float mn = fmaxf(m_i[i][r], mc[i][r]);
        alpha[i][r] = exp2f((m_i[i][r] - mn) * LOG2E);
        m_i[i][r] = mn;
        l_i[i][r] *= alpha[i][r];
      }
#pragma unroll
    for (int i = 0; i < 2; i++)
#pragma unroll
      for (int j = 0; j < 8; j++)
#pragma unroll
        for (int r = 0; r < 4; r++) {
          float s = S[i][j][r];
          float p = (s < -1e29f) ? 0.f : exp2f((s - m_i[i][r]) * LOG2E);
          S[i][j][r] = p;
          l_i[i][r] += p;   // per-lane partial row-sum; reduced at the end
        }
#pragma unroll
    for (int i = 0; i < 2; i++)
#pragma unroll
      for (int jd = 0; jd < 8; jd++)
#pragma unroll
        for (int r = 0; r < 4; r++) O[i][jd][r] *= alpha[i][r];
    __syncthreads();   // all QK reads of KP done before overwriting with P
#pragma unroll
    for (int i = 0; i < 2; i++)
#pragma unroll
      for (int j = 0; j < 8; j++)
#pragma unroll
        for (int r = 0; r < 4; r++)
          KP[(32 * wave + 16 * i + q4 * 4 + r) * 128 + 16 * j + l16] = f2bf(S[i][j][r]);
    __syncthreads();
    // O += P V : K-dim = 128 keys
#pragma unroll
    for (int ks = 0; ks < 4; ks++) {
      bf16x8 pf0 = *(const bf16x8*)(&KP[(32 * wave + l16) * 128 + ks * 32 + q4 * 8]);
      bf16x8 pf1 = *(const bf16x8*)(&KP[(32 * wave + 16 + l16) * 128 + ks * 32 + q4 * 8]);
#pragma unroll
      for (int jd = 0; jd < 8; jd++) {
        bf16x8 vf = *(const bf16x8*)(&Vt[(16 * jd + l16) * 128 + ks * 32 + q4 * 8]);
        O[0][jd] = __builtin_amdgcn_mfma_f32_16x16x32_bf16(pf0, vf, O[0][jd], 0, 0, 0);
        O[1][jd] = __builtin_amdgcn_mfma_f32_16x16x32_bf16(pf1, vf, O[1][jd], 0, 0, 0);
      }
    }
  }
  // final cross-lane l reduction (rows live in 16-lane groups within a quad)
#pragma unroll
  for (int d = 1; d < 16; d <<= 1)
#pragma unroll
    for (int i = 0; i < 2; i++)
#pragma unroll
      for (int r = 0; r < 4; r++)
        l_i[i][r] += __shfl_xor(l_i[i][r], d, 64);
#pragma unroll
  for (int i = 0; i < 2; i++)
#pragma unroll
    for (int r = 0; r < 4; r++) {
      float inv = 1.0f / l_i[i][r];
      long row = (long)(b * T_ + t0 + 32 * wave + 16 * i + q4 * 4 + r);
#pragma unroll
      for (int jd = 0; jd < 8; jd++)
        y[row * 2048 + h * HD + 16 * jd + l16] = f2bf(O[i][jd][r] * inv);
    }
}

// ---------------- launcher ----------------
extern "C" void kernel_launch(void* const* d_in, const int* in_sizes, int n_in,
                              void* d_out, int out_size, void* d_ws, size_t ws_size,
                              hipStream_t stream) {
  const float* x    = (const float*)d_in[0];
  const float* wq   = (const float*)d_in[1];
  const float* wk   = (const float*)d_in[2];
  const float* wv   = (const float*)d_in[3];
  const float* wo   = (const float*)d_in[4];
  const float* rope = (const float*)d_in[5];
  float* out = (float*)d_out;

  // workspace layout (u16 elements); yb aliases xb (x dead after QKV GEMM)
  u16* xb   = (u16*)d_ws;                       // 8192*2048
  u16* wqkv = xb + (long)8192 * 2048;           // 3072*2048  (wq|wk|wv rows)
  u16* wob  = wqkv + (long)3072 * 2048;         // 2048*2048
  u16* qkv  = wob + (long)2048 * 2048;          // 8192*3072
  u16* yb   = xb;                               // 8192*2048 (reuse)

  {
    long n = (long)8192 * 2048;
    cvt_f32_bf16<<<dim3((unsigned)((n / 4 + 255) / 256)), dim3(256), 0, stream>>>(x, xb, (int)n);
    n = (long)2048 * 2048;
    cvt_f32_bf16<<<dim3((unsigned)((n / 4 + 255) / 256)), dim3(256), 0, stream>>>(wq, wqkv, (int)n);
    n = (long)512 * 2048;
    cvt_f32_bf16<<<dim3((unsigned)((n / 4 + 255) / 256)), dim3(256), 0, stream>>>(
        wk, wqkv + (long)2048 * 2048, (int)n);
    cvt_f32_bf16<<<dim3((unsigned)((n / 4 + 255) / 256)), dim3(256), 0, stream>>>(
        wv, wqkv + (long)2048 * 2048 + (long)512 * 2048, (int)n);
    n = (long)2048 * 2048;
    cvt_f32_bf16<<<dim3((unsigned)((n / 4 + 255) / 256)), dim3(256), 0, stream>>>(wo, wob, (int)n);
  }

  // QKV projection: [8192,2048] x [3072,2048]^T -> qkv [8192,3072] bf16
  gemm_bt<1><<<dim3(3072 / 128, 8192 / 128), dim3(256), 0, stream>>>(
      xb, wqkv, (void*)qkv, 8192, 3072, 2048);

  long npairs = (long)B_ * T_ * (NH + NKV) * (HD / 2);
  rope_kernel<<<dim3((unsigned)((npairs + 255) / 256)), dim3(256), 0, stream>>>(qkv, rope);

  attn_kernel<<<dim3(NH, T_ / 128, B_), dim3(256), 0, stream>>>(qkv, yb);

  // output projection: y [8192,2048] x wo [2048,2048]^T -> out f32
  gemm_bt<0><<<dim3(2048 / 128, 8192 / 128), dim3(256), 0, stream>>>(
      yb, wob, (void*)out, 8192, 2048, 2048);
}

// Round 2
// 539.619 us; speedup vs baseline: 1.0640x; 1.0640x over previous
//
#include <hip/hip_runtime.h>
#include <stdint.h>

typedef unsigned short u16;
typedef __attribute__((ext_vector_type(8))) short bf16x8;      // 8 bf16 = 4 VGPRs
typedef __attribute__((ext_vector_type(8))) unsigned short u16x8;
typedef __attribute__((ext_vector_type(4))) float f32x4;

#define B_  2
#define T_  4096
#define C_  2048
#define NH  16
#define NKV 4
#define HD  128

__device__ __forceinline__ u16 f2bf(float f) {
  union { float f; uint32_t u; } v; v.f = f;
  uint32_t u = v.u;
  u += 0x7fffu + ((u >> 16) & 1u);   // RNE
  return (u16)(u >> 16);
}
__device__ __forceinline__ float bf2f(u16 h) {
  union { uint32_t u; float f; } v; v.u = ((uint32_t)h) << 16;
  return v.f;
}

__device__ __forceinline__ void gload_lds16(const u16* g, u16* l) {
  __builtin_amdgcn_global_load_lds(
      (const __attribute__((address_space(1))) void*)g,
      (__attribute__((address_space(3))) void*)l, 16, 0, 0);
}

// ---------------- f32 -> bf16 convert ----------------
__global__ void cvt_f32_bf16(const float* __restrict__ src, u16* __restrict__ dst, int n) {
  int i = (blockIdx.x * blockDim.x + threadIdx.x) * 4;
  if (i >= n) return;
  float4 v = *(const float4*)(src + i);
  ushort4 o;
  o.x = f2bf(v.x); o.y = f2bf(v.y); o.z = f2bf(v.z); o.w = f2bf(v.w);
  *(ushort4*)(dst + i) = o;
}

// ---------------- in-place RoPE on qkv buffer [B*T][3072] ----------------
__global__ void rope_kernel(u16* __restrict__ qkv, const float* __restrict__ cache) {
  const int PH = (NH + NKV) * (HD / 2);   // 1280 pairs per row
  long idx = (long)blockIdx.x * blockDim.x + threadIdx.x;
  if (idx >= (long)B_ * T_ * PH) return;
  int row = (int)(idx / PH);
  int rem = (int)(idx % PH);
  int hh = rem >> 6;
  int i  = rem & 63;
  int t  = row & (T_ - 1);
  float c = cache[t * 128 + 2 * i];
  float s = cache[t * 128 + 2 * i + 1];
  u16* p = qkv + (long)row * 3072 + hh * HD + 2 * i;
  float x0 = bf2f(p[0]), x1 = bf2f(p[1]);
  p[0] = f2bf(x0 * c - x1 * s);
  p[1] = f2bf(x0 * s + x1 * c);
}

// ---------------- bf16 GEMM: C[M][N] = A[M][K] * B[N][K]^T ----------------
// m97 structure: 128x128 tile, BK=32, global_load_lds width-16 staging.
// LDS physical layout = load order; lane->chunk map XOR-swizzles columns so
// fragment ds_read_b128 are <=2-way conflicted (free per m136).
template <int WRITE_BF16>
__global__ __launch_bounds__(256) void gemm_bt(const u16* __restrict__ A,
                                               const u16* __restrict__ Bw,
                                               void* __restrict__ Cv,
                                               int M, int N, int K) {
  constexpr int BK = 32;
  __shared__ u16 As[128 * BK];   // 8 KB, 8 regions of 1024 B
  __shared__ u16 Bs[128 * BK];
  const int tid = threadIdx.x;
  const int wave = tid >> 6, lane = tid & 63;
  const int q4 = lane >> 4, l16 = lane & 15;
  const long m0 = (long)blockIdx.y * 128, n0 = (long)blockIdx.x * 128;
  const int wm = (wave >> 1) * 64, wn = (wave & 1) * 64;

  // staging map: wave handles regions wave*2+{0,1} of each buffer.
  // region = 16 rows x 4 chunks(16B). lane l -> row lrow=l>>2, logical cb = (l&3)^(lrow&3)
  const int lrow = lane >> 2;
  const int lcb  = (lane & 3) ^ (lrow & 3);
  const int r0   = wave * 32 + lrow;          // rows of region wave*2
  const int r1   = r0 + 16;                   // rows of region wave*2+1
  const u16* Ag0 = A + (m0 + r0) * K + lcb * 8;
  const u16* Ag1 = A + (m0 + r1) * K + lcb * 8;
  const u16* Bg0 = Bw + (n0 + r0) * K + lcb * 8;
  const u16* Bg1 = Bw + (n0 + r1) * K + lcb * 8;
  u16* Al0 = As + (wave * 2 + 0) * 512 + lane * 8;
  u16* Al1 = As + (wave * 2 + 1) * 512 + lane * 8;
  u16* Bl0 = Bs + (wave * 2 + 0) * 512 + lane * 8;
  u16* Bl1 = Bs + (wave * 2 + 1) * 512 + lane * 8;

  const int swz = (q4 ^ (l16 & 3)) << 3;   // physical chunk offset for logical cb=q4
  f32x4 acc[4][4] = {};
  for (int k0 = 0; k0 < K; k0 += BK) {
    gload_lds16(Ag0 + k0, Al0);
    gload_lds16(Ag1 + k0, Al1);
    gload_lds16(Bg0 + k0, Bl0);
    gload_lds16(Bg1 + k0, Bl1);
    __syncthreads();
    bf16x8 af[4], bfr[4];
#pragma unroll
    for (int i = 0; i < 4; i++)
      af[i] = *(const bf16x8*)(As + (wm + 16 * i + l16) * BK + swz);
#pragma unroll
    for (int j = 0; j < 4; j++)
      bfr[j] = *(const bf16x8*)(Bs + (wn + 16 * j + l16) * BK + swz);
#pragma unroll
    for (int i = 0; i < 4; i++)
#pragma unroll
      for (int j = 0; j < 4; j++)
        acc[i][j] = __builtin_amdgcn_mfma_f32_16x16x32_bf16(af[i], bfr[j], acc[i][j], 0, 0, 0);
    __syncthreads();
  }
  // C/D layout: col = lane&15, row = (lane>>4)*4 + reg   [measured m89]
  if (WRITE_BF16) {
    u16* Cp = (u16*)Cv;
#pragma unroll
    for (int i = 0; i < 4; i++)
#pragma unroll
      for (int j = 0; j < 4; j++)
#pragma unroll
        for (int r = 0; r < 4; r++)
          Cp[(m0 + wm + 16 * i + q4 * 4 + r) * (long)N + n0 + wn + 16 * j + l16] =
              f2bf(acc[i][j][r]);
  } else {
    float* Cp = (float*)Cv;
#pragma unroll
    for (int i = 0; i < 4; i++)
#pragma unroll
      for (int j = 0; j < 4; j++)
#pragma unroll
        for (int r = 0; r < 4; r++)
          Cp[(m0 + wm + 16 * i + q4 * 4 + r) * (long)N + n0 + wn + 16 * j + l16] =
              acc[i][j][r];
  }
}

// ---------------- sliding-window attention ----------------
// XOR-swizzled LDS: element (row,col) lives at row*128 + ((col>>3 ^ (row&15))<<3) + (col&7)
__device__ __forceinline__ int swzi(int row, int col) {
  return row * 128 + ((((col >> 3) ^ (row & 15)) << 3) | (col & 7));
}

__global__ __launch_bounds__(256) void attn_kernel(const u16* __restrict__ qkv,
                                                   u16* __restrict__ y) {
  const int h = blockIdx.x, tc = blockIdx.y, b = blockIdx.z;
  const int t0 = tc * 128;
  const int kvh = h >> 2;
  __shared__ u16 KP[128 * 128];   // K chunk [key][d]; later P [q][key]  (swizzled)
  __shared__ u16 Vt[128 * 128];   // V^T chunk [d][key]                  (swizzled)
  const int tid = threadIdx.x;
  const int wave = tid >> 6, lane = tid & 63;
  const int q4 = lane >> 4, l16 = lane & 15;
  const float scale = 0.08838834764831845f;   // 1/sqrt(128)
  const float LOG2E = 1.4426950408889634f;

  bf16x8 qf[2][4];
#pragma unroll
  for (int i = 0; i < 2; i++)
#pragma unroll
    for (int ks = 0; ks < 4; ks++) {
      const u16* src = qkv + ((long)(b * T_ + t0 + 32 * wave + 16 * i + l16)) * 3072 +
                       h * HD + ks * 32 + q4 * 8;
      qf[i][ks] = *(const bf16x8*)src;
    }

  f32x4 O[2][8] = {};
  float m_i[2][4], l_i[2][4];
#pragma unroll
  for (int i = 0; i < 2; i++)
#pragma unroll
    for (int r = 0; r < 4; r++) { m_i[i][r] = -1e30f; l_i[i][r] = 0.f; }

  int kstart = t0 - 256; if (kstart < 0) kstart = 0;
  for (int k0 = kstart; k0 <= t0; k0 += 128) {
    __syncthreads();
    {
      int key = tid & 127, db = (tid >> 7) * 64;
      const u16* kg = qkv + ((long)(b * T_ + k0 + key)) * 3072 + C_ + kvh * HD + db;
      const u16* vg = kg + NKV * HD;
#pragma unroll
      for (int j2 = 0; j2 < 8; j2++) {
        u16x8 kk = *(const u16x8*)(kg + 8 * j2);
        *(u16x8*)(&KP[swzi(key, db + 8 * j2)]) = kk;
        u16x8 vv = *(const u16x8*)(vg + 8 * j2);
#pragma unroll
        for (int e = 0; e < 8; e++) Vt[swzi(db + 8 * j2 + e, key)] = vv[e];
      }
    }
    __syncthreads();
    // S = Q K^T
    f32x4 S[2][8] = {};
#pragma unroll
    for (int ks = 0; ks < 4; ks++)
#pragma unroll
      for (int j = 0; j < 8; j++) {
        bf16x8 kf = *(const bf16x8*)(&KP[swzi(16 * j + l16, ks * 32 + q4 * 8)]);
        S[0][j] = __builtin_amdgcn_mfma_f32_16x16x32_bf16(qf[0][ks], kf, S[0][j], 0, 0, 0);
        S[1][j] = __builtin_amdgcn_mfma_f32_16x16x32_bf16(qf[1][ks], kf, S[1][j], 0, 0, 0);
      }
    float mc[2][4];
#pragma unroll
    for (int i = 0; i < 2; i++)
#pragma unroll
      for (int r = 0; r < 4; r++) mc[i][r] = -1e30f;
#pragma unroll
    for (int i = 0; i < 2; i++)
#pragma unroll
      for (int j = 0; j < 8; j++)
#pragma unroll
        for (int r = 0; r < 4; r++) {
          float s = S[i][j][r] * scale;
          int trow = t0 + 32 * wave + 16 * i + q4 * 4 + r;
          int kcol = k0 + 16 * j + l16;
          bool valid = (kcol <= trow) && (kcol + 255 >= trow);
          s = valid ? s : -1e30f;
          S[i][j][r] = s;
          mc[i][r] = fmaxf(mc[i][r], s);
        }
#pragma unroll
    for (int d = 1; d < 16; d <<= 1)
#pragma unroll
      for (int i = 0; i < 2; i++)
#pragma unroll
        for (int r = 0; r < 4; r++)
          mc[i][r] = fmaxf(mc[i][r], __shfl_xor(mc[i][r], d, 64));
    float alpha[2][4];
#pragma unroll
    for (int i = 0; i < 2; i++)
#pragma unroll
      for (int r = 0; r < 4; r++) {
        float mn = fmaxf(m_i[i][r], mc[i][r]);
        alpha[i][r] = exp2f((m_i[i][r] - mn) * LOG2E);
        m_i[i][r] = mn;
        l_i[i][r] *= alpha[i][r];
      }
#pragma unroll
    for (int i = 0; i < 2; i++)
#pragma unroll
      for (int j = 0; j < 8; j++)
#pragma unroll
        for (int r = 0; r < 4; r++) {
          float s = S[i][j][r];
          float p = (s < -1e29f) ? 0.f : exp2f((s - m_i[i][r]) * LOG2E);
          S[i][j][r] = p;
          l_i[i][r] += p;
        }
#pragma unroll
    for (int i = 0; i < 2; i++)
#pragma unroll
      for (int jd = 0; jd < 8; jd++)
#pragma unroll
        for (int r = 0; r < 4; r++) O[i][jd][r] *= alpha[i][r];
    __syncthreads();
#pragma unroll
    for (int i = 0; i < 2; i++)
#pragma unroll
      for (int j = 0; j < 8; j++)
#pragma unroll
        for (int r = 0; r < 4; r++)
          KP[swzi(32 * wave + 16 * i + q4 * 4 + r, 16 * j + l16)] = f2bf(S[i][j][r]);
    __syncthreads();
    // O += P V
#pragma unroll
    for (int ks = 0; ks < 4; ks++) {
      bf16x8 pf0 = *(const bf16x8*)(&KP[swzi(32 * wave + l16, ks * 32 + q4 * 8)]);
      bf16x8 pf1 = *(const bf16x8*)(&KP[swzi(32 * wave + 16 + l16, ks * 32 + q4 * 8)]);
#pragma unroll
      for (int jd = 0; jd < 8; jd++) {
        bf16x8 vf = *(const bf16x8*)(&Vt[swzi(16 * jd + l16, ks * 32 + q4 * 8)]);
        O[0][jd] = __builtin_amdgcn_mfma_f32_16x16x32_bf16(pf0, vf, O[0][jd], 0, 0, 0);
        O[1][jd] = __builtin_amdgcn_mfma_f32_16x16x32_bf16(pf1, vf, O[1][jd], 0, 0, 0);
      }
    }
  }
#pragma unroll
  for (int d = 1; d < 16; d <<= 1)
#pragma unroll
    for (int i = 0; i < 2; i++)
#pragma unroll
      for (int r = 0; r < 4; r++)
        l_i[i][r] += __shfl_xor(l_i[i][r], d, 64);
#pragma unroll
  for (int i = 0; i < 2; i++)
#pragma unroll
    for (int r = 0; r < 4; r++) {
      float inv = 1.0f / l_i[i][r];
      long row = (long)(b * T_ + t0 + 32 * wave + 16 * i + q4 * 4 + r);
#pragma unroll
      for (int jd = 0; jd < 8; jd++)
        y[row * 2048 + h * HD + 16 * jd + l16] = f2bf(O[i][jd][r] * inv);
    }
}

// ---------------- launcher ----------------
extern "C" void kernel_launch(void* const* d_in, const int* in_sizes, int n_in,
                              void* d_out, int out_size, void* d_ws, size_t ws_size,
                              hipStream_t stream) {
  const float* x    = (const float*)d_in[0];
  const float* wq   = (const float*)d_in[1];
  const float* wk   = (const float*)d_in[2];
  const float* wv   = (const float*)d_in[3];
  const float* wo   = (const float*)d_in[4];
  const float* rope = (const float*)d_in[5];
  float* out = (float*)d_out;

  u16* xb   = (u16*)d_ws;                       // 8192*2048
  u16* wqkv = xb + (long)8192 * 2048;           // 3072*2048
  u16* wob  = wqkv + (long)3072 * 2048;         // 2048*2048
  u16* qkv  = wob + (long)2048 * 2048;          // 8192*3072
  u16* yb   = xb;                               // reuse

  {
    long n = (long)8192 * 2048;
    cvt_f32_bf16<<<dim3((unsigned)((n / 4 + 255) / 256)), dim3(256), 0, stream>>>(x, xb, (int)n);
    n = (long)2048 * 2048;
    cvt_f32_bf16<<<dim3((unsigned)((n / 4 + 255) / 256)), dim3(256), 0, stream>>>(wq, wqkv, (int)n);
    n = (long)512 * 2048;
    cvt_f32_bf16<<<dim3((unsigned)((n / 4 + 255) / 256)), dim3(256), 0, stream>>>(
        wk, wqkv + (long)2048 * 2048, (int)n);
    cvt_f32_bf16<<<dim3((unsigned)((n / 4 + 255) / 256)), dim3(256), 0, stream>>>(
        wv, wqkv + (long)2048 * 2048 + (long)512 * 2048, (int)n);
    n = (long)2048 * 2048;
    cvt_f32_bf16<<<dim3((unsigned)((n / 4 + 255) / 256)), dim3(256), 0, stream>>>(wo, wob, (int)n);
  }

  gemm_bt<1><<<dim3(3072 / 128, 8192 / 128), dim3(256), 0, stream>>>(
      xb, wqkv, (void*)qkv, 8192, 3072, 2048);

  long npairs = (long)B_ * T_ * (NH + NKV) * (HD / 2);
  rope_kernel<<<dim3((unsigned)((npairs + 255) / 256)), dim3(256), 0, stream>>>(qkv, rope);

  attn_kernel<<<dim3(NH, T_ / 128, B_), dim3(256), 0, stream>>>(qkv, yb);

  gemm_bt<0><<<dim3(2048 / 128, 8192 / 128), dim3(256), 0, stream>>>(
      yb, wob, (void*)out, 8192, 2048, 2048);
}